// Round 6
// baseline (960.040 us; speedup 1.0000x reference)
//
#include <hip/hip_runtime.h>
#include <math.h>

// Problem constants
#define BB   32
#define NN   200
#define SS   192
#define FIN  8
#define HH   64
#define PP   48
#define FNN  4
#define KK   10
#define NBLK 3
#define EPSF 1e-5f
#define SH   (SS*HH)               // 12288
#define XSZ  ((size_t)BB*NN*SS*HH) // 78,643,200 elements
#define ROWS (BB*NN)               // 6400

// Swizzled transposed-tile geometry (both temporal and spatial):
//   elem (row, c) at u16 [row*256 + ((((c>>3) ^ ((row>>1)&31))&31)<<3) + (c&7)]
#define XSW   256
// spatial final-output region stride (u16), union over xT allocation
#define FSP   68
// AbF: fragment-ordered adjacency [ks=14][nt=7][lane=64][8]
#define ABFSZ (14*7*512)           // 50176 u16

typedef __attribute__((ext_vector_type(8))) short bf16x8;
typedef __attribute__((ext_vector_type(4))) float f32x4;
typedef __attribute__((ext_vector_type(16))) float f32x16;

// bf16 <-> f32 helpers on raw ushort storage
__device__ __forceinline__ float bf2f(unsigned short u) {
    union { unsigned int i; float f; } v; v.i = ((unsigned int)u) << 16; return v.f;
}
__device__ __forceinline__ unsigned short f2bf(float f) {
    union { float f; unsigned int i; } v; v.f = f;
    unsigned int r = v.i + 0x7FFFu + ((v.i >> 16) & 1u);   // round-nearest-even
    return (unsigned short)(r >> 16);
}
// R15: HW packed bf16 convert (RNE), 1 inst for 2 values (no builtin; T12 recipe)
__device__ __forceinline__ unsigned int cvtpk(float lo, float hi) {
    unsigned int r;
    asm("v_cvt_pk_bf16_f32 %0, %1, %2" : "=v"(r) : "v"(lo), "v"(hi));
    return r;
}

__device__ __forceinline__ float wave_sum(float v) {
    #pragma unroll
    for (int off = 32; off > 0; off >>= 1) v += __shfl_xor(v, off, 64);
    return v;
}
__device__ __forceinline__ float wave_max(float v) {
    #pragma unroll
    for (int off = 32; off > 0; off >>= 1) v = fmaxf(v, __shfl_xor(v, off, 64));
    return v;
}

// ---------------------------------------------------------------------------
// Adjacency: la = relu(E E^T); top-K mask; softmax; blend with adj; diag=1;
// store un-normalized row + d_r. One wave per row.
// ---------------------------------------------------------------------------
__global__ void k_adj_row(const float* __restrict__ emb, const float* __restrict__ adj,
                          const float* __restrict__ alpha_p,
                          float* __restrict__ Araw, float* __restrict__ dvec) {
    int r = blockIdx.x;
    int lane = threadIdx.x;
    __shared__ float er[HH];
    __shared__ float la[NN];
    __shared__ float tmp[NN];
    __shared__ float keep[NN];
    er[lane] = emb[r*HH + lane];
    __syncthreads();
    for (int j = lane; j < NN; j += 64) {
        float d = 0.f;
        #pragma unroll 8
        for (int h = 0; h < HH; ++h) d += er[h] * emb[j*HH + h];
        float v = fmaxf(d, 0.f);
        la[j] = v; tmp[j] = v; keep[j] = 0.f;
    }
    __syncthreads();
    for (int it = 0; it < KK; ++it) {
        float bv = -1.f; int bi = NN;
        for (int j = lane; j < NN; j += 64) {
            float v = tmp[j];
            if (v > bv) { bv = v; bi = j; }
        }
        #pragma unroll
        for (int off = 32; off > 0; off >>= 1) {
            float ov = __shfl_xor(bv, off, 64);
            int   oi = __shfl_xor(bi, off, 64);
            if (ov > bv || (ov == bv && oi < bi)) { bv = ov; bi = oi; }
        }
        if (lane == 0) { keep[bi] = 1.f; tmp[bi] = -1.f; }
        __syncthreads();
    }
    float mloc = 0.f;
    for (int j = lane; j < NN; j += 64) {
        float v = (keep[j] > 0.f) ? la[j] : 0.f;
        tmp[j] = v;
        mloc = fmaxf(mloc, v);
    }
    float m = wave_max(mloc);
    float sloc = 0.f;
    for (int j = lane; j < NN; j += 64) sloc += expf(tmp[j] - m);
    float ssum = wave_sum(sloc);
    float alpha = alpha_p[0];
    float rloc = 0.f;
    for (int j = lane; j < NN; j += 64) {
        float soft = expf(tmp[j] - m) / ssum;
        float comb = alpha * adj[r*NN + j] + (1.f - alpha) * soft;
        float a = (j == r) ? 1.f : comb;
        Araw[r*NN + j] = a;
        rloc += a;
    }
    float rs = wave_sum(rloc);
    if (lane == 0) dvec[r] = 1.f / sqrtf(fmaxf(rs, 1.f));
}

__global__ void k_adj_scale(const float* __restrict__ Araw, const float* __restrict__ dvec,
                            float* __restrict__ Amat) {
    int r = blockIdx.x, j = threadIdx.x;
    if (j < NN) Amat[r*NN + j] = Araw[r*NN + j] * dvec[r] * dvec[j];
}

// ---------------------------------------------------------------------------
// Prep: cast tW -> bf16; build FRAGMENT-ORDERED adjacency AbF and gcn weights
// gWF for the 32x32x16 spatial MFMAs:
//   AbF[((ks*7 + nt)*64 + l)*8 + j] = A[node = nt*32+(l&31)][k = ks*16+(l>>5)*8+j]
//   gWF[blk][((ksh*2 + nt2)*64 + l)*8 + j] = gW[blk][h = ksh*16+(l>>5)*8+j][h' = nt2*32+(l&31)]
// Also fragment-ordered per-h' constants for the transposed-MFMA2 epilogue:
//   {gbF,lnwF,lnbF}[blk][u][mt*16+r] = v[blk*64 + 32mt+(r&3)+8(r>>2)+4u]
// ---------------------------------------------------------------------------
__global__ void k_prep(const float* __restrict__ tW, const float* __restrict__ gW,
                       const float* __restrict__ Amat, const float* __restrict__ gb,
                       const float* __restrict__ lnw, const float* __restrict__ lnb,
                       unsigned short* __restrict__ tWb,
                       unsigned short* __restrict__ AbF, unsigned short* __restrict__ gWF,
                       float* __restrict__ gbF, float* __restrict__ lnwF,
                       float* __restrict__ lnbF) {
    int i = blockIdx.x*256 + threadIdx.x;
    if (i < NBLK*SS*SS) tWb[i] = f2bf(tW[i]);
    if (i < ABFSZ) {
        int j = i & 7, l = (i >> 3) & 63;
        int nt = (i >> 9) % 7, ks = i / (7*512);
        int node = nt*32 + (l & 31);
        int k = ks*16 + (l >> 5)*8 + j;
        AbF[i] = (node < NN && k < NN) ? f2bf(Amat[node*NN + k]) : (unsigned short)0;
    }
    if (i < NBLK*4096) {
        int blk = i >> 12, r = i & 4095;
        int j = r & 7, l = (r >> 3) & 63;
        int nt2 = (r >> 9) & 1, ksh = r >> 10;
        int h = ksh*16 + (l >> 5)*8 + j;
        int hp = nt2*32 + (l & 31);
        gWF[i] = f2bf(gW[(blk << 12) + h*HH + hp]);
    }
    if (i < NBLK*64) {
        int blk = i >> 6, u = (i >> 5) & 1, mt = (i >> 4) & 1, r = i & 15;
        int hp = 32*mt + (r & 3) + 8*(r >> 2) + 4*u;
        gbF[i]  = gb[blk*HH + hp];
        lnwF[i] = lnw[blk*HH + hp];
        lnbF[i] = lnb[blk*HH + hp];
    }
}

// ---------------------------------------------------------------------------
// Prep2 (head): hWT[n][k] = bf16(head_W[k][n]) for k < SH;
//   C1[j=p2*4+f][p] = sum_h fW[f,h]*hW[SH+p2*64+h][p]   (futr branch folded)
//   c0[p] = hb[p] + sum_{p2,h} fb[h]*hW[SH+p2*64+h][p]
// ---------------------------------------------------------------------------
__global__ void k_prep2(const float* __restrict__ hW, const float* __restrict__ fW,
                        const float* __restrict__ fb, const float* __restrict__ hb,
                        unsigned short* __restrict__ hWT, float* __restrict__ C1,
                        float* __restrict__ c0) {
    int i = blockIdx.x*256 + threadIdx.x;
    if (i < PP*SH) {
        int n = i / SH, k = i % SH;
        hWT[i] = f2bf(hW[(size_t)k*PP + n]);
    }
    if (i < PP*FNN*PP) {            // 192*48
        int j = i / PP, p = i % PP;
        int p2 = j >> 2, f = j & 3;
        float s = 0.f;
        #pragma unroll 8
        for (int h = 0; h < HH; ++h)
            s += fW[f*HH + h] * hW[(size_t)(SH + p2*HH + h)*PP + p];
        C1[i] = s;
    }
    if (i < PP) {
        float s = hb[i];
        for (int c = 0; c < PP*HH; ++c)
            s += fb[c & 63] * hW[(size_t)(SH + c)*PP + i];
        c0[i] = s;
    }
}

// ---------------------------------------------------------------------------
// Shared temporal MFMA body: xT = swizzled tile, row = h, col = s.
// R15: MFMA operands SWAPPED (A/B fragment lane layouts identical) so the
// D row dim = h (memory-consecutive per lane): lane holds y[t = w*48+tt*16+col]
// [h = ht*16+q*4+r]. Epilogue: 12 b64 global stores (was 48 u16 stores) and
// 24 cvt_pk (was 48 software f2bf). Residual: 48 u16 LDS gathers (swizzle
// spreads rows across banks). gelu uses v_rcp_f32.
// ---------------------------------------------------------------------------
__device__ __forceinline__ void temporal_mfma_body(const unsigned short* xT,
        unsigned short* __restrict__ xp, const unsigned short* __restrict__ Wb,
        const float* __restrict__ tb, int tid) {
    int lane = tid & 63, w = tid >> 6;
    int col = lane & 15, q = lane >> 4;
    f32x4 acc[3][4];
    #pragma unroll
    for (int tt = 0; tt < 3; ++tt)
        #pragma unroll
        for (int ht = 0; ht < 4; ++ht) acc[tt][ht] = (f32x4){0.f,0.f,0.f,0.f};

    #pragma unroll 2
    for (int k0 = 0; k0 < SS; k0 += 32) {
        bf16x8 a[3], b[4];
        int kc = (k0 >> 3) + q;
        #pragma unroll
        for (int tt = 0; tt < 3; ++tt)
            a[tt] = *(const bf16x8*)(Wb + (size_t)(w*48 + tt*16 + col)*SS + k0 + q*8);
        #pragma unroll
        for (int ht = 0; ht < 4; ++ht) {
            int row = ht*16 + col;
            b[ht] = *(const bf16x8*)(&xT[row*XSW + (((kc ^ ((row>>1)&31)) & 31)<<3)]);
        }
        #pragma unroll
        for (int tt = 0; tt < 3; ++tt)
            #pragma unroll
            for (int ht = 0; ht < 4; ++ht)
                acc[tt][ht] = __builtin_amdgcn_mfma_f32_16x16x32_bf16(b[ht], a[tt], acc[tt][ht], 0, 0, 0);
    }
    // acc[tt][ht][r] = y[t = w*48+tt*16+col][h = ht*16+q*4+r]
    #pragma unroll
    for (int tt = 0; tt < 3; ++tt) {
        int t = w*48 + tt*16 + col;
        float tbv = tb[t];
        int tk = t >> 3, t7 = t & 7;
        #pragma unroll
        for (int ht = 0; ht < 4; ++ht) {
            int h0 = ht*16 + q*4;
            float v[4];
            #pragma unroll
            for (int r = 0; r < 4; ++r) {
                int h = h0 + r;
                float y = acc[tt][ht][r] + tbv;
                // gelu(y) ~= y * sigmoid(2*0.7978845608*(y + 0.044715 y^3))
                float u2 = y * (1.5957691216f + 0.07135481626f*y*y);
                float g = y * __builtin_amdgcn_rcpf(1.f + __expf(-u2));
                unsigned short xr = xT[h*XSW + (((tk ^ ((h>>1)&31)) & 31)<<3) + t7];
                v[r] = bf2f(xr) + g;
            }
            unsigned int o0 = cvtpk(v[0], v[1]), o1 = cvtpk(v[2], v[3]);
            unsigned long long pk = (unsigned long long)o0 | ((unsigned long long)o1 << 32);
            *(unsigned long long*)(xp + (size_t)t*HH + h0) = pk;
        }
    }
}

// ---------------------------------------------------------------------------
// Fused stage0 + temporal block 0: InstanceNorm over S (per b,n,f) -> proj
// (8->64) -> +emb computed straight into the swizzled xT LDS tile, then the
// temporal MFMA body. LDS = exactly 32 KB (5 blocks/CU).
// ---------------------------------------------------------------------------
__global__ __launch_bounds__(256) void k_stage0_temporal(
        const float* __restrict__ x, const float* __restrict__ inw,
        const float* __restrict__ inb, const float* __restrict__ pW,
        const float* __restrict__ pb, const float* __restrict__ emb,
        unsigned short* __restrict__ X, const unsigned short* __restrict__ Wb,
        const float* __restrict__ tb) {
    __shared__ unsigned short xT[HH * XSW];   // 32 KB exactly
    float* redf = (float*)xT;                 // 64-float scratch in xT row 0 (pre-projection)
    int bn = blockIdx.x, tid = threadIdx.x;
    int n = bn % NN;
    int lane = tid & 63, w = tid >> 6;
    const float* xin = x + (size_t)bn*SS*FIN;
    // per-lane register staging: sl = w*8 + (lane>>3), f0 = lane&7
    int f0 = lane & 7, sl = w*8 + (lane >> 3);
    float xv[6];
    #pragma unroll
    for (int j = 0; j < 6; ++j) xv[j] = xin[(sl*6 + j)*FIN + f0];
    float s1 = 0.f, s2 = 0.f;
    #pragma unroll
    for (int j = 0; j < 6; ++j) { s1 += xv[j]; s2 += xv[j]*xv[j]; }
    #pragma unroll
    for (int off = 8; off <= 32; off <<= 1) {
        s1 += __shfl_xor(s1, off, 64);
        s2 += __shfl_xor(s2, off, 64);
    }
    if (lane < FIN) { redf[w*16 + lane] = s1; redf[w*16 + 8 + lane] = s2; }
    __syncthreads();
    int h = lane;
    float sp8[FIN];
    float cst = pb[h] + emb[n*HH + h];
    #pragma unroll
    for (int f = 0; f < FIN; ++f) {
        float a  = redf[0*16 + f] + redf[1*16 + f] + redf[2*16 + f] + redf[3*16 + f];
        float b2 = redf[0*16+8+f] + redf[1*16+8+f] + redf[2*16+8+f] + redf[3*16+8+f];
        float mu  = a * (1.f/SS);
        float var = b2 * (1.f/SS) - mu*mu;
        float sc  = inw[f] * __builtin_amdgcn_rsqf(var + EPSF);
        float pw  = pW[f*HH + h];
        sp8[f] = sc * pw;
        cst += (inb[f] - mu*sc) * pw;
    }
    __syncthreads();                          // scratch consumed before xT writes
    // wave-uniform base -> scalar re-reads of this wave's 1.5 KB x-chunk (L1-hot)
    const float* xw = xin + (size_t)__builtin_amdgcn_readfirstlane(w * 48 * FIN);
    int key = (h >> 1) & 31;
    for (int j4 = 0; j4 < 12; ++j4) {
        int s0 = w*48 + j4*4;
        float accv[4];
        #pragma unroll
        for (int r = 0; r < 4; ++r) {
            float acc = cst;
            #pragma unroll
            for (int f = 0; f < FIN; ++f) acc += xw[j4*32 + r*FIN + f] * sp8[f];
            accv[r] = acc;
        }
        unsigned int o0 = cvtpk(accv[0], accv[1]), o1 = cvtpk(accv[2], accv[3]);
        unsigned long long pk = (unsigned long long)o0 | ((unsigned long long)o1 << 32);
        *(unsigned long long*)(&xT[h*XSW + ((((s0>>3) ^ key) & 31)<<3) + (s0&7)]) = pk;
    }
    __syncthreads();
    temporal_mfma_body(xT, X + (size_t)bn*SH, Wb, tb, tid);
}

// ---------------------------------------------------------------------------
// Temporal MFMA (IN-PLACE), iterations 1..: stage X row into swizzled xT via
// dword-pair micro-transpose, then shared body. LDS = 32 KB exactly.
// ---------------------------------------------------------------------------
__global__ __launch_bounds__(256) void k_temporal_mfma(unsigned short* __restrict__ X,
        const unsigned short* __restrict__ Wb, const float* __restrict__ tb) {
    __shared__ unsigned short xT[HH * XSW];   // 32 KB
    unsigned int* sm32 = (unsigned int*)xT;
    int bn = blockIdx.x, tid = threadIdx.x;
    unsigned short* xp = X + (size_t)bn*SH;
    const unsigned int* xp32 = (const unsigned int*)xp;
    for (int i = tid; i < 96*32; i += 256) {
        int sp = i >> 5, hp = i & 31;
        unsigned int u0 = xp32[(2*sp)*32 + hp];
        unsigned int u1 = xp32[(2*sp+1)*32 + hp];
        unsigned int lo = (u0 & 0xffffu) | (u1 << 16);          // h=2hp  @ s,s+1
        unsigned int hi = (u0 >> 16) | (u1 & 0xffff0000u);      // h=2hp+1
        int swz = ((((sp>>2) ^ hp) & 31)<<2) + (sp&3);
        sm32[(2*hp)*128 + swz]   = lo;
        sm32[(2*hp+1)*128 + swz] = hi;
    }
    __syncthreads();
    temporal_mfma_body(xT, xp, Wb, tb, tid);
}

// ---------------------------------------------------------------------------
// Fused spatial (IN-PLACE on X), 512 threads / 8 waves, 32x32x16 MFMA:
//   z[node,h] = sum_n A[node,n] x[b,n,s',h]        (MFMA1, K=224)
//   y[node,h'] = z[node,:] @ gcn_W                 (MFMA2, K=64)
//   x = LN_h'( x + y + gb ) * ln_w + ln_b
// R14 structure (transposed MFMA2, lane-local LN); R15: cvt_pk for all
// f32->bf16 pair conversions (repack 16 insts, epilogue 16 insts).
// ---------------------------------------------------------------------------
__global__ __launch_bounds__(512) void k_spatial_fused(unsigned short* __restrict__ X,
        const unsigned short* __restrict__ AbF, const unsigned short* __restrict__ gWF,
        const float* __restrict__ gbF, const float* __restrict__ lnwF,
        const float* __restrict__ lnbF) {
    __shared__ unsigned short smem[HH * XSW];    // 32 KB: xT, later final-out (union)
    unsigned int* sm32 = (unsigned int*)smem;
    // bijective XCD decomposition: phys = idx*8 + xcd; XCD x -> sp in [24x,24x+24)
    int phys = blockIdx.x;
    int xcd = phys & 7, idx = phys >> 3;         // idx in [0,768)
    int b = idx / 24;
    int sp = xcd * 24 + (idx - b * 24);
    int tid = threadIdx.x;
    unsigned short* xbase = X + (size_t)b*NN*SH + sp*HH;
    const unsigned int* xp32 = (const unsigned int*)xbase;

    // stage xT: elem (h, n) -> row h, col n (swizzled, key = (h>>1)&31)
    for (int i = tid; i < 100*32; i += 512) {
        int np = i >> 5, dd = i & 31;            // node pair, h-dword
        unsigned int u0 = xp32[(size_t)(2*np)*(SH/2) + dd];
        unsigned int u1 = xp32[(size_t)(2*np+1)*(SH/2) + dd];
        unsigned int lo = (u0 & 0xffffu) | (u1 << 16);          // h=2dd
        unsigned int hi = (u0 >> 16) | (u1 & 0xffff0000u);      // h=2dd+1
        int swz = ((((np>>2) ^ dd) & 31)<<2) + (np&3);          // key = dd
        sm32[(2*dd)*128 + swz]   = lo;
        sm32[(2*dd+1)*128 + swz] = hi;
    }
    // zero-pad node cols 200..223 (dword cols 100..111)
    for (int i = tid; i < 64*12; i += 512) {
        int r = i / 12, kdw = 100 + (i % 12);
        sm32[r*128 + ((((kdw>>2) ^ ((r>>1)&31)) & 31)<<2) + (kdw&3)] = 0;
    }
    __syncthreads();

    int lane = tid & 63, w = tid >> 6;           // w in 0..7; w<7 compute node-tile w
    int l31 = lane & 31, u = lane >> 5;
    int nd = w*32 + l31;                         // this lane's node (MFMA2 D col)

    f32x16 acc2[2];                              // yT: [mt: h'-half][16 regs]
    float mu = 0.f, rstd = 0.f;

    if (w < 7) {
        // ---- MFMA1: a = xT[h][nn] (LDS, swizzled), b = AbF (global, coalesced) ----
        f32x16 acc1[2];
        #pragma unroll
        for (int ht = 0; ht < 2; ++ht)
            #pragma unroll
            for (int e = 0; e < 16; ++e) acc1[ht][e] = 0.f;
        const unsigned short* abp = AbF + (size_t)w*512 + lane*8;
        #pragma unroll
        for (int ks = 0; ks < 14; ++ks) {
            bf16x8 bb = *(const bf16x8*)(abp + (size_t)ks*7*512);
            #pragma unroll
            for (int ht = 0; ht < 2; ++ht) {
                int row = ht*32 + l31;
                int chunk = ks*2 + u;
                bf16x8 a = *(const bf16x8*)(&smem[row*XSW +
                        (((chunk ^ ((row>>1)&31)) & 31)<<3)]);
                acc1[ht] = __builtin_amdgcn_mfma_f32_32x32x16_bf16(a, bb, acc1[ht], 0, 0, 0);
            }
        }
        // z value at reg r: z[h = 32ht + (r&3)+8(r>>2)+4u][node = w*32 + l31]
        // pack pairs (regs 2k, 2k+1) -> bf16 dword; swap halves for z K-frags
        unsigned int Dw[2][8], Xw[2][8];
        #pragma unroll
        for (int ht = 0; ht < 2; ++ht)
            #pragma unroll
            for (int k = 0; k < 8; ++k)
                Dw[ht][k] = cvtpk(acc1[ht][2*k], acc1[ht][2*k+1]);
        #pragma unroll
        for (int ht = 0; ht < 2; ++ht)
            #pragma unroll
            for (int k = 0; k < 8; ++k)
                Xw[ht][k] = (unsigned int)__shfl_xor((int)Dw[ht][k], 32, 64);

        // ---- MFMA2 (SWAPPED): A = gWF (global), B = z-frags (regs) ----
        #pragma unroll
        for (int mt = 0; mt < 2; ++mt)
            #pragma unroll
            for (int e = 0; e < 16; ++e) acc2[mt][e] = 0.f;
        const unsigned short* gp = gWF + lane*8;
        #pragma unroll
        for (int ht = 0; ht < 2; ++ht)
            #pragma unroll
            for (int s = 0; s < 2; ++s) {
                int ksh = ht*2 + s;
                union { unsigned int w4[4]; bf16x8 v; } a2;
                if (s == 0) {
                    a2.w4[0] = u ? Xw[ht][2] : Dw[ht][0];
                    a2.w4[1] = u ? Xw[ht][3] : Dw[ht][1];
                    a2.w4[2] = u ? Dw[ht][2] : Xw[ht][0];
                    a2.w4[3] = u ? Dw[ht][3] : Xw[ht][1];
                } else {
                    a2.w4[0] = u ? Xw[ht][6] : Dw[ht][4];
                    a2.w4[1] = u ? Xw[ht][7] : Dw[ht][5];
                    a2.w4[2] = u ? Dw[ht][6] : Xw[ht][4];
                    a2.w4[3] = u ? Dw[ht][7] : Xw[ht][5];
                }
                #pragma unroll
                for (int mt = 0; mt < 2; ++mt) {
                    bf16x8 bw = *(const bf16x8*)(gp + (size_t)(ksh*2 + mt)*512);
                    acc2[mt] = __builtin_amdgcn_mfma_f32_32x32x16_bf16(bw, a2.v, acc2[mt], 0, 0, 0);
                }
            }

        // ---- residual gather (xT, transposed layout) + gb, then LN stats ----
        // acc2[mt][r] = y[h' = 32mt+(r&3)+8(r>>2)+4u][node nd]
        const f32x4* gb4 = (const f32x4*)(gbF + u*32);
        #pragma unroll
        for (int mt = 0; mt < 2; ++mt)
            #pragma unroll
            for (int rq = 0; rq < 4; ++rq) {
                f32x4 g = gb4[mt*4 + rq];
                #pragma unroll
                for (int j = 0; j < 4; ++j) {
                    int hp = 32*mt + 8*rq + 4*u + j;
                    unsigned short xr = smem[hp*XSW +
                        ((((nd>>3) ^ ((hp>>1)&31)) & 31)<<3) + (nd&7)];
                    acc2[mt][rq*4 + j] += bf2f(xr) + g[j];
                }
            }
        float s1 = 0.f, s2 = 0.f;
        #pragma unroll
        for (int mt = 0; mt < 2; ++mt)
            #pragma unroll
            for (int r = 0; r < 16; ++r) {
                float v = acc2[mt][r];
                s1 += v; s2 += v*v;
            }
        s1 += __shfl_xor(s1, 32, 64);            // combine with partner u-half
        s2 += __shfl_xor(s2, 32, 64);
        mu = s1 * (1.f/64.f);
        float var = s2 * (1.f/64.f) - mu*mu;
        rstd = __builtin_amdgcn_rsqf(var + EPSF);
    }
    __syncthreads();                             // all xT reads complete

    if (w < 7 && nd < NN) {
        // ---- affine + pack 4 consecutive h' -> b64 stores into FSP region ----
        const f32x4* lw4 = (const f32x4*)(lnwF + u*32);
        const f32x4* lb4 = (const f32x4*)(lnbF + u*32);
        #pragma unroll
        for (int mt = 0; mt < 2; ++mt)
            #pragma unroll
            for (int rq = 0; rq < 4; ++rq) {
                f32x4 lw = lw4[mt*4 + rq], lb = lb4[mt*4 + rq];
                float o0 = (acc2[mt][rq*4 + 0] - mu) * rstd * lw[0] + lb[0];
                float o1 = (acc2[mt][rq*4 + 1] - mu) * rstd * lw[1] + lb[1];
                float o2 = (acc2[mt][rq*4 + 2] - mu) * rstd * lw[2] + lb[2];
                float o3 = (acc2[mt][rq*4 + 3] - mu) * rstd * lw[3] + lb[3];
                unsigned int d0 = cvtpk(o0, o1), d1 = cvtpk(o2, o3);
                unsigned long long pk = (unsigned long long)d0 | ((unsigned long long)d1 << 32);
                *(unsigned long long*)(&smem[nd*FSP + 32*mt + 8*rq + 4*u]) = pk;
            }
    }
    __syncthreads();
    // ---- coalesced write-out: full 128 B line per node (b128 chunks) ----
    for (int i = tid; i < NN*8; i += 512) {
        int node = i >> 3, c16 = i & 7;
        uint4 vv = *(const uint4*)(&smem[node*FSP + c16*8]);
        *(uint4*)(xbase + (size_t)node*SH + c16*8) = vv;
    }
}

// ---------------------------------------------------------------------------
// Head futr+bias: out[row,p] = c0[p] + xfut[row,:192] @ C1   (plain writes,
// runs BEFORE k_head_mfma which atomically accumulates the hist GEMM)
// ---------------------------------------------------------------------------
__global__ __launch_bounds__(192) void k_head_futr(const float* __restrict__ xfut,
        const float* __restrict__ C1, const float* __restrict__ c0,
        float* __restrict__ out) {
    __shared__ float C1l[192*PP];   // 36.8 KB
    __shared__ float xfl[4*192];    // 3 KB
    int tid = threadIdx.x;
    int r0 = blockIdx.x * 4;
    for (int i = tid; i < 192*PP; i += 192) C1l[i] = C1[i];
    for (int i = tid; i < 4*192; i += 192) xfl[i] = xfut[(size_t)r0*192 + i];
    __syncthreads();
    int p = tid % PP, rr = tid / PP;
    float acc = c0[p];
    #pragma unroll 8
    for (int j = 0; j < 192; ++j) acc += xfl[rr*192 + j] * C1l[j*PP + p];
    out[(size_t)(r0 + rr)*PP + p] = acc;
}

// ---------------------------------------------------------------------------
// Head hist GEMM (bf16 MFMA): out[row,p] += X[row,:12288] @ hWT^T
// A-op = X rows straight from global; B-op = hWT (L2-hot). Split-K x8.
// ---------------------------------------------------------------------------
#define KSL 1536
__global__ __launch_bounds__(256) void k_head_mfma(const unsigned short* __restrict__ X,
        const unsigned short* __restrict__ hWT, float* __restrict__ out) {
    int tid = threadIdx.x;
    int lane = tid & 63, w = tid >> 6;
    int col = lane & 15, q = lane >> 4;
    int m0 = blockIdx.x*64 + w*16;
    int k0 = blockIdx.y*KSL;
    const unsigned short* xp = X + (size_t)(m0 + col)*SH + k0 + q*8;
    const unsigned short* wp = hWT + (size_t)col*SH + k0 + q*8;
    f32x4 acc[3];
    #pragma unroll
    for (int nt = 0; nt < 3; ++nt) acc[nt] = (f32x4){0.f,0.f,0.f,0.f};
    #pragma unroll 4
    for (int kk = 0; kk < KSL; kk += 32) {
        bf16x8 a = *(const bf16x8*)(xp + kk);
        #pragma unroll
        for (int nt = 0; nt < 3; ++nt) {
            bf16x8 b = *(const bf16x8*)(wp + (size_t)nt*16*SH + kk);
            acc[nt] = __builtin_amdgcn_mfma_f32_16x16x32_bf16(a, b, acc[nt], 0, 0, 0);
        }
    }
    int orow = m0 + q*4;
    #pragma unroll
    for (int nt = 0; nt < 3; ++nt)
        #pragma unroll
        for (int r = 0; r < 4; ++r)
            atomicAdd(&out[(size_t)(orow + r)*PP + nt*16 + col], acc[nt][r]);
}

// ---------------------------------------------------------------------------
extern "C" void kernel_launch(void* const* d_in, const int* in_sizes, int n_in,
                              void* d_out, int out_size, void* d_ws, size_t ws_size,
                              hipStream_t stream) {
    const float* x     = (const float*)d_in[0];
    const float* xfut  = (const float*)d_in[1];
    const float* adj   = (const float*)d_in[2];
    const float* emb   = (const float*)d_in[3];
    const float* alpha = (const float*)d_in[4];
    const float* inw   = (const float*)d_in[5];
    const float* inb   = (const float*)d_in[6];
    const float* pW    = (const float*)d_in[7];
    const float* pb    = (const float*)d_in[8];
    const float* tW    = (const float*)d_in[9];
    const float* tb    = (const float*)d_in[10];
    const float* gW    = (const float*)d_in[11];
    const float* gb    = (const float*)d_in[12];
    const float* lnw   = (const float*)d_in[13];
    const float* lnb   = (const float*)d_in[14];
    const float* fW    = (const float*)d_in[15];
    const float* fb    = (const float*)d_in[16];
    const float* hW    = (const float*)d_in[17];
    const float* hb    = (const float*)d_in[18];
    float* out = (float*)d_out;

    // Workspace layout (~160 MB): bufX 157.3MB + adjacency/weights ~1.6MB
    unsigned short* bufX = (unsigned short*)d_ws;
    float* Amat = (float*)(bufX + XSZ);
    float* Araw = Amat + NN*NN;
    float* dvec = Araw + NN*NN;
    unsigned short* tWb = (unsigned short*)(dvec + NN);
    unsigned short* AbF = tWb + NBLK*SS*SS;
    unsigned short* gWF = AbF + ABFSZ;
    unsigned short* hWT = gWF + NBLK*HH*HH;
    float* C1 = (float*)(hWT + (size_t)PP*SH);
    float* c0 = C1 + 192*PP;
    float* gbF  = c0 + PP;
    float* lnwF = gbF + NBLK*64;
    float* lnbF = lnwF + NBLK*64;

    k_adj_row<<<NN, 64, 0, stream>>>(emb, adj, alpha, Araw, dvec);
    k_adj_scale<<<NN, 256, 0, stream>>>(Araw, dvec, Amat);
    k_prep<<<(NBLK*SS*SS + 255)/256, 256, 0, stream>>>(tW, gW, Amat, gb, lnw, lnb,
                                                       tWb, AbF, gWF, gbF, lnwF, lnbF);
    k_prep2<<<((size_t)PP*SH + 255)/256, 256, 0, stream>>>(hW, fW, fb, hb, hWT, C1, c0);

    // fused stage0 + temporal block 0
    k_stage0_temporal<<<ROWS, 256, 0, stream>>>(x, inw, inb, pW, pb, emb, bufX, tWb, tb);
    k_spatial_fused<<<dim3(SS*BB), 512, 0, stream>>>(bufX, AbF, gWF, gbF, lnwF, lnbF);
    for (int i = 1; i < NBLK; ++i) {
        k_temporal_mfma<<<ROWS, 256, 0, stream>>>(bufX, tWb + (size_t)i*SS*SS, tb + i*SS);
        k_spatial_fused<<<dim3(SS*BB), 512, 0, stream>>>(bufX, AbF, gWF + (size_t)i*HH*HH,
                                                         gbF + i*64, lnwF + i*64, lnbF + i*64);
    }
    k_head_futr<<<ROWS/4, 192, 0, stream>>>(xfut, C1, c0, out);
    k_head_mfma<<<dim3(ROWS/64, 8), 256, 0, stream>>>(bufX, hWT, out);
}

// Round 7
// 922.242 us; speedup vs baseline: 1.0410x; 1.0410x over previous
//
#include <hip/hip_runtime.h>
#include <math.h>

// Problem constants
#define BB   32
#define NN   200
#define SS   192
#define FIN  8
#define HH   64
#define PP   48
#define FNN  4
#define KK   10
#define NBLK 3
#define EPSF 1e-5f
#define SH   (SS*HH)               // 12288
#define XSZ  ((size_t)BB*NN*SS*HH) // 78,643,200 elements
#define ROWS (BB*NN)               // 6400

// Swizzled transposed-tile geometry (both temporal and spatial):
//   elem (row, c) at u16 [row*256 + ((((c>>3) ^ ((row>>1)&31))&31)<<3) + (c&7)]
#define XSW   256
// spatial final-output region stride (u16), union over xT allocation
#define FSP   68
// AbF: fragment-ordered adjacency [ks=14][nt=7][lane=64][8]
#define ABFSZ (14*7*512)           // 50176 u16

typedef __attribute__((ext_vector_type(8))) short bf16x8;
typedef __attribute__((ext_vector_type(4))) float f32x4;
typedef __attribute__((ext_vector_type(16))) float f32x16;

// bf16 <-> f32 helpers on raw ushort storage
__device__ __forceinline__ float bf2f(unsigned short u) {
    union { unsigned int i; float f; } v; v.i = ((unsigned int)u) << 16; return v.f;
}
__device__ __forceinline__ unsigned short f2bf(float f) {
    union { float f; unsigned int i; } v; v.f = f;
    unsigned int r = v.i + 0x7FFFu + ((v.i >> 16) & 1u);   // round-nearest-even
    return (unsigned short)(r >> 16);
}
// HW packed bf16 convert (RNE), 1 inst for 2 values (no builtin; T12 recipe)
__device__ __forceinline__ unsigned int cvtpk(float lo, float hi) {
    unsigned int r;
    asm("v_cvt_pk_bf16_f32 %0, %1, %2" : "=v"(r) : "v"(lo), "v"(hi));
    return r;
}

__device__ __forceinline__ float wave_sum(float v) {
    #pragma unroll
    for (int off = 32; off > 0; off >>= 1) v += __shfl_xor(v, off, 64);
    return v;
}
__device__ __forceinline__ float wave_max(float v) {
    #pragma unroll
    for (int off = 32; off > 0; off >>= 1) v = fmaxf(v, __shfl_xor(v, off, 64));
    return v;
}

// ---------------------------------------------------------------------------
// Adjacency: la = relu(E E^T); top-K mask; softmax; blend with adj; diag=1;
// store un-normalized row + d_r. One wave per row.
// ---------------------------------------------------------------------------
__global__ void k_adj_row(const float* __restrict__ emb, const float* __restrict__ adj,
                          const float* __restrict__ alpha_p,
                          float* __restrict__ Araw, float* __restrict__ dvec) {
    int r = blockIdx.x;
    int lane = threadIdx.x;
    __shared__ float er[HH];
    __shared__ float la[NN];
    __shared__ float tmp[NN];
    __shared__ float keep[NN];
    er[lane] = emb[r*HH + lane];
    __syncthreads();
    for (int j = lane; j < NN; j += 64) {
        float d = 0.f;
        #pragma unroll 8
        for (int h = 0; h < HH; ++h) d += er[h] * emb[j*HH + h];
        float v = fmaxf(d, 0.f);
        la[j] = v; tmp[j] = v; keep[j] = 0.f;
    }
    __syncthreads();
    for (int it = 0; it < KK; ++it) {
        float bv = -1.f; int bi = NN;
        for (int j = lane; j < NN; j += 64) {
            float v = tmp[j];
            if (v > bv) { bv = v; bi = j; }
        }
        #pragma unroll
        for (int off = 32; off > 0; off >>= 1) {
            float ov = __shfl_xor(bv, off, 64);
            int   oi = __shfl_xor(bi, off, 64);
            if (ov > bv || (ov == bv && oi < bi)) { bv = ov; bi = oi; }
        }
        if (lane == 0) { keep[bi] = 1.f; tmp[bi] = -1.f; }
        __syncthreads();
    }
    float mloc = 0.f;
    for (int j = lane; j < NN; j += 64) {
        float v = (keep[j] > 0.f) ? la[j] : 0.f;
        tmp[j] = v;
        mloc = fmaxf(mloc, v);
    }
    float m = wave_max(mloc);
    float sloc = 0.f;
    for (int j = lane; j < NN; j += 64) sloc += expf(tmp[j] - m);
    float ssum = wave_sum(sloc);
    float alpha = alpha_p[0];
    float rloc = 0.f;
    for (int j = lane; j < NN; j += 64) {
        float soft = expf(tmp[j] - m) / ssum;
        float comb = alpha * adj[r*NN + j] + (1.f - alpha) * soft;
        float a = (j == r) ? 1.f : comb;
        Araw[r*NN + j] = a;
        rloc += a;
    }
    float rs = wave_sum(rloc);
    if (lane == 0) dvec[r] = 1.f / sqrtf(fmaxf(rs, 1.f));
}

__global__ void k_adj_scale(const float* __restrict__ Araw, const float* __restrict__ dvec,
                            float* __restrict__ Amat) {
    int r = blockIdx.x, j = threadIdx.x;
    if (j < NN) Amat[r*NN + j] = Araw[r*NN + j] * dvec[r] * dvec[j];
}

// ---------------------------------------------------------------------------
// Prep: build FRAGMENT-ORDERED tables so every MFMA B/A-operand load is one
// fully-coalesced 1KB dwordx4 read:
//   tWbF[blk][((w*6+kk)*3+tt)*512 + l*8+j] = tW[blk][t = w*48+tt*16+(l&15)]
//                                               [s = kk*32+(l>>4)*8+j]
//   AbF[((ks*7 + nt)*64 + l)*8 + j] = A[node = nt*32+(l&31)][k = ks*16+(l>>5)*8+j]
//   gWF[blk][((ksh*2 + nt2)*64 + l)*8 + j] = gW[blk][h = ksh*16+(l>>5)*8+j][h' = nt2*32+(l&31)]
// Also fragment-ordered per-h' constants for the transposed-MFMA2 epilogue:
//   {gbF,lnwF,lnbF}[blk][u][mt*16+r] = v[blk*64 + 32mt+(r&3)+8(r>>2)+4u]
// ---------------------------------------------------------------------------
__global__ void k_prep(const float* __restrict__ tW, const float* __restrict__ gW,
                       const float* __restrict__ Amat, const float* __restrict__ gb,
                       const float* __restrict__ lnw, const float* __restrict__ lnb,
                       unsigned short* __restrict__ tWb,
                       unsigned short* __restrict__ AbF, unsigned short* __restrict__ gWF,
                       float* __restrict__ gbF, float* __restrict__ lnwF,
                       float* __restrict__ lnbF) {
    int i = blockIdx.x*256 + threadIdx.x;
    if (i < NBLK*SS*SS) {
        int blk = i / (SS*SS), r = i % (SS*SS);
        int j = r & 7, l = (r >> 3) & 63;
        int g = r >> 9;
        int tt = g % 3, kk = (g / 3) % 6, w = g / 18;
        int t = w*48 + tt*16 + (l & 15);
        int s = kk*32 + (l >> 4)*8 + j;
        tWb[i] = f2bf(tW[blk*SS*SS + t*SS + s]);
    }
    if (i < ABFSZ) {
        int j = i & 7, l = (i >> 3) & 63;
        int nt = (i >> 9) % 7, ks = i / (7*512);
        int node = nt*32 + (l & 31);
        int k = ks*16 + (l >> 5)*8 + j;
        AbF[i] = (node < NN && k < NN) ? f2bf(Amat[node*NN + k]) : (unsigned short)0;
    }
    if (i < NBLK*4096) {
        int blk = i >> 12, r = i & 4095;
        int j = r & 7, l = (r >> 3) & 63;
        int nt2 = (r >> 9) & 1, ksh = r >> 10;
        int h = ksh*16 + (l >> 5)*8 + j;
        int hp = nt2*32 + (l & 31);
        gWF[i] = f2bf(gW[(blk << 12) + h*HH + hp]);
    }
    if (i < NBLK*64) {
        int blk = i >> 6, u = (i >> 5) & 1, mt = (i >> 4) & 1, r = i & 15;
        int hp = 32*mt + (r & 3) + 8*(r >> 2) + 4*u;
        gbF[i]  = gb[blk*HH + hp];
        lnwF[i] = lnw[blk*HH + hp];
        lnbF[i] = lnb[blk*HH + hp];
    }
}

// ---------------------------------------------------------------------------
// Prep2 (head): hWT[n][k] = bf16(head_W[k][n]) for k < SH;
//   C1[j=p2*4+f][p] = sum_h fW[f,h]*hW[SH+p2*64+h][p]   (futr branch folded)
//   c0[p] = hb[p] + sum_{p2,h} fb[h]*hW[SH+p2*64+h][p]
// ---------------------------------------------------------------------------
__global__ void k_prep2(const float* __restrict__ hW, const float* __restrict__ fW,
                        const float* __restrict__ fb, const float* __restrict__ hb,
                        unsigned short* __restrict__ hWT, float* __restrict__ C1,
                        float* __restrict__ c0) {
    int i = blockIdx.x*256 + threadIdx.x;
    if (i < PP*SH) {
        int n = i / SH, k = i % SH;
        hWT[i] = f2bf(hW[(size_t)k*PP + n]);
    }
    if (i < PP*FNN*PP) {            // 192*48
        int j = i / PP, p = i % PP;
        int p2 = j >> 2, f = j & 3;
        float s = 0.f;
        #pragma unroll 8
        for (int h = 0; h < HH; ++h)
            s += fW[f*HH + h] * hW[(size_t)(SH + p2*HH + h)*PP + p];
        C1[i] = s;
    }
    if (i < PP) {
        float s = hb[i];
        for (int c = 0; c < PP*HH; ++c)
            s += fb[c & 63] * hW[(size_t)(SH + c)*PP + i];
        c0[i] = s;
    }
}

// ---------------------------------------------------------------------------
// Shared temporal MFMA body: xT = swizzled tile, row = h, col = s.
// Swapped operands: lane holds y[t = w*48+tt*16+col][h = ht*16+q*4+r].
// R16: A-frags from fragment-ordered tWbF (coalesced 1KB loads, was 16-row
// gathers). Residual: RESG ? b64 global loads from xp (per-element single-
// lane ownership + data dependence => race-free) : LDS u16 gathers (stage0).
// ---------------------------------------------------------------------------
template<bool RESG>
__device__ __forceinline__ void temporal_mfma_body(const unsigned short* xT,
        unsigned short* __restrict__ xp, const unsigned short* __restrict__ Wb,
        const float* __restrict__ tb, int tid) {
    int lane = tid & 63, w = tid >> 6;
    int col = lane & 15, q = lane >> 4;
    f32x4 acc[3][4];
    #pragma unroll
    for (int tt = 0; tt < 3; ++tt)
        #pragma unroll
        for (int ht = 0; ht < 4; ++ht) acc[tt][ht] = (f32x4){0.f,0.f,0.f,0.f};

    const unsigned short* wbp = Wb + (size_t)(w*18)*512 + lane*8;
    #pragma unroll 2
    for (int k0 = 0; k0 < SS; k0 += 32) {
        int kk = k0 >> 5;
        bf16x8 a[3], b[4];
        int kc = (k0 >> 3) + q;
        #pragma unroll
        for (int tt = 0; tt < 3; ++tt)
            a[tt] = *(const bf16x8*)(wbp + (size_t)(kk*3 + tt)*512);
        #pragma unroll
        for (int ht = 0; ht < 4; ++ht) {
            int row = ht*16 + col;
            b[ht] = *(const bf16x8*)(&xT[row*XSW + (((kc ^ ((row>>1)&31)) & 31)<<3)]);
        }
        #pragma unroll
        for (int tt = 0; tt < 3; ++tt)
            #pragma unroll
            for (int ht = 0; ht < 4; ++ht)
                acc[tt][ht] = __builtin_amdgcn_mfma_f32_16x16x32_bf16(b[ht], a[tt], acc[tt][ht], 0, 0, 0);
    }
    // acc[tt][ht][r] = y[t = w*48+tt*16+col][h = ht*16+q*4+r]
    #pragma unroll
    for (int tt = 0; tt < 3; ++tt) {
        int t = w*48 + tt*16 + col;
        float tbv = tb[t];
        int tk = t >> 3, t7 = t & 7;
        #pragma unroll
        for (int ht = 0; ht < 4; ++ht) {
            int h0 = ht*16 + q*4;
            unsigned long long rr = 0;
            if (RESG) rr = *(const unsigned long long*)(xp + (size_t)t*HH + h0);
            float v[4];
            #pragma unroll
            for (int r = 0; r < 4; ++r) {
                int h = h0 + r;
                float y = acc[tt][ht][r] + tbv;
                // gelu(y) ~= y * sigmoid(2*0.7978845608*(y + 0.044715 y^3))
                float u2 = y * (1.5957691216f + 0.07135481626f*y*y);
                float g = y * __builtin_amdgcn_rcpf(1.f + __expf(-u2));
                unsigned short xr;
                if (RESG) xr = (unsigned short)(rr >> (16*r));
                else      xr = xT[h*XSW + (((tk ^ ((h>>1)&31)) & 31)<<3) + t7];
                v[r] = bf2f(xr) + g;
            }
            unsigned int o0 = cvtpk(v[0], v[1]), o1 = cvtpk(v[2], v[3]);
            unsigned long long pk = (unsigned long long)o0 | ((unsigned long long)o1 << 32);
            *(unsigned long long*)(xp + (size_t)t*HH + h0) = pk;
        }
    }
}

// ---------------------------------------------------------------------------
// Fused stage0 + temporal block 0: InstanceNorm over S (per b,n,f) -> proj
// (8->64) -> +emb computed straight into the swizzled xT LDS tile, then the
// temporal MFMA body. LDS = exactly 32 KB (5 blocks/CU).
// ---------------------------------------------------------------------------
__global__ __launch_bounds__(256) void k_stage0_temporal(
        const float* __restrict__ x, const float* __restrict__ inw,
        const float* __restrict__ inb, const float* __restrict__ pW,
        const float* __restrict__ pb, const float* __restrict__ emb,
        unsigned short* __restrict__ X, const unsigned short* __restrict__ Wb,
        const float* __restrict__ tb) {
    __shared__ unsigned short xT[HH * XSW];   // 32 KB exactly
    float* redf = (float*)xT;                 // 64-float scratch in xT row 0 (pre-projection)
    int bn = blockIdx.x, tid = threadIdx.x;
    int n = bn % NN;
    int lane = tid & 63, w = tid >> 6;
    const float* xin = x + (size_t)bn*SS*FIN;
    // per-lane register staging: sl = w*8 + (lane>>3), f0 = lane&7
    int f0 = lane & 7, sl = w*8 + (lane >> 3);
    float xv[6];
    #pragma unroll
    for (int j = 0; j < 6; ++j) xv[j] = xin[(sl*6 + j)*FIN + f0];
    float s1 = 0.f, s2 = 0.f;
    #pragma unroll
    for (int j = 0; j < 6; ++j) { s1 += xv[j]; s2 += xv[j]*xv[j]; }
    #pragma unroll
    for (int off = 8; off <= 32; off <<= 1) {
        s1 += __shfl_xor(s1, off, 64);
        s2 += __shfl_xor(s2, off, 64);
    }
    if (lane < FIN) { redf[w*16 + lane] = s1; redf[w*16 + 8 + lane] = s2; }
    __syncthreads();
    int h = lane;
    float sp8[FIN];
    float cst = pb[h] + emb[n*HH + h];
    #pragma unroll
    for (int f = 0; f < FIN; ++f) {
        float a  = redf[0*16 + f] + redf[1*16 + f] + redf[2*16 + f] + redf[3*16 + f];
        float b2 = redf[0*16+8+f] + redf[1*16+8+f] + redf[2*16+8+f] + redf[3*16+8+f];
        float mu  = a * (1.f/SS);
        float var = b2 * (1.f/SS) - mu*mu;
        float sc  = inw[f] * __builtin_amdgcn_rsqf(var + EPSF);
        float pw  = pW[f*HH + h];
        sp8[f] = sc * pw;
        cst += (inb[f] - mu*sc) * pw;
    }
    __syncthreads();                          // scratch consumed before xT writes
    // wave-uniform base -> scalar re-reads of this wave's 1.5 KB x-chunk (L1-hot)
    const float* xw = xin + (size_t)__builtin_amdgcn_readfirstlane(w * 48 * FIN);
    int key = (h >> 1) & 31;
    for (int j4 = 0; j4 < 12; ++j4) {
        int s0 = w*48 + j4*4;
        float accv[4];
        #pragma unroll
        for (int r = 0; r < 4; ++r) {
            float acc = cst;
            #pragma unroll
            for (int f = 0; f < FIN; ++f) acc += xw[j4*32 + r*FIN + f] * sp8[f];
            accv[r] = acc;
        }
        unsigned int o0 = cvtpk(accv[0], accv[1]), o1 = cvtpk(accv[2], accv[3]);
        unsigned long long pk = (unsigned long long)o0 | ((unsigned long long)o1 << 32);
        *(unsigned long long*)(&xT[h*XSW + ((((s0>>3) ^ key) & 31)<<3) + (s0&7)]) = pk;
    }
    __syncthreads();
    temporal_mfma_body<false>(xT, X + (size_t)bn*SH, Wb, tb, tid);
}

// ---------------------------------------------------------------------------
// Temporal MFMA (IN-PLACE), iterations 1..: stage X row into swizzled xT via
// dword-pair micro-transpose, then shared body (residual from global).
// ---------------------------------------------------------------------------
__global__ __launch_bounds__(256) void k_temporal_mfma(unsigned short* __restrict__ X,
        const unsigned short* __restrict__ Wb, const float* __restrict__ tb) {
    __shared__ unsigned short xT[HH * XSW];   // 32 KB
    unsigned int* sm32 = (unsigned int*)xT;
    int bn = blockIdx.x, tid = threadIdx.x;
    unsigned short* xp = X + (size_t)bn*SH;
    const unsigned int* xp32 = (const unsigned int*)xp;
    for (int i = tid; i < 96*32; i += 256) {
        int sp = i >> 5, hp = i & 31;
        unsigned int u0 = xp32[(2*sp)*32 + hp];
        unsigned int u1 = xp32[(2*sp+1)*32 + hp];
        unsigned int lo = (u0 & 0xffffu) | (u1 << 16);          // h=2hp  @ s,s+1
        unsigned int hi = (u0 >> 16) | (u1 & 0xffff0000u);      // h=2hp+1
        int swz = ((((sp>>2) ^ hp) & 31)<<2) + (sp&3);
        sm32[(2*hp)*128 + swz]   = lo;
        sm32[(2*hp+1)*128 + swz] = hi;
    }
    __syncthreads();
    temporal_mfma_body<true>(xT, xp, Wb, tb, tid);
}

// ---------------------------------------------------------------------------
// Fused spatial (IN-PLACE on X), 512 threads / 8 waves, 32x32x16 MFMA:
//   z[node,h] = sum_n A[node,n] x[b,n,s',h]        (MFMA1, K=224)
//   y[node,h'] = z[node,:] @ gcn_W                 (MFMA2, K=64)
//   x = LN_h'( x + y + gb ) * ln_w + ln_b
// Transposed MFMA2, lane-local LN, cvt_pk conversions, XCD-aware grid.
// ---------------------------------------------------------------------------
__global__ __launch_bounds__(512) void k_spatial_fused(unsigned short* __restrict__ X,
        const unsigned short* __restrict__ AbF, const unsigned short* __restrict__ gWF,
        const float* __restrict__ gbF, const float* __restrict__ lnwF,
        const float* __restrict__ lnbF) {
    __shared__ unsigned short smem[HH * XSW];    // 32 KB: xT, later final-out (union)
    unsigned int* sm32 = (unsigned int*)smem;
    // bijective XCD decomposition: phys = idx*8 + xcd; XCD x -> sp in [24x,24x+24)
    int phys = blockIdx.x;
    int xcd = phys & 7, idx = phys >> 3;         // idx in [0,768)
    int b = idx / 24;
    int sp = xcd * 24 + (idx - b * 24);
    int tid = threadIdx.x;
    unsigned short* xbase = X + (size_t)b*NN*SH + sp*HH;
    const unsigned int* xp32 = (const unsigned int*)xbase;

    // stage xT: elem (h, n) -> row h, col n (swizzled, key = (h>>1)&31)
    for (int i = tid; i < 100*32; i += 512) {
        int np = i >> 5, dd = i & 31;            // node pair, h-dword
        unsigned int u0 = xp32[(size_t)(2*np)*(SH/2) + dd];
        unsigned int u1 = xp32[(size_t)(2*np+1)*(SH/2) + dd];
        unsigned int lo = (u0 & 0xffffu) | (u1 << 16);          // h=2dd
        unsigned int hi = (u0 >> 16) | (u1 & 0xffff0000u);      // h=2dd+1
        int swz = ((((np>>2) ^ dd) & 31)<<2) + (np&3);          // key = dd
        sm32[(2*dd)*128 + swz]   = lo;
        sm32[(2*dd+1)*128 + swz] = hi;
    }
    // zero-pad node cols 200..223 (dword cols 100..111)
    for (int i = tid; i < 64*12; i += 512) {
        int r = i / 12, kdw = 100 + (i % 12);
        sm32[r*128 + ((((kdw>>2) ^ ((r>>1)&31)) & 31)<<2) + (kdw&3)] = 0;
    }
    __syncthreads();

    int lane = tid & 63, w = tid >> 6;           // w in 0..7; w<7 compute node-tile w
    int l31 = lane & 31, u = lane >> 5;
    int nd = w*32 + l31;                         // this lane's node (MFMA2 D col)

    f32x16 acc2[2];                              // yT: [mt: h'-half][16 regs]
    float mu = 0.f, rstd = 0.f;

    if (w < 7) {
        // ---- MFMA1: a = xT[h][nn] (LDS, swizzled), b = AbF (global, coalesced) ----
        f32x16 acc1[2];
        #pragma unroll
        for (int ht = 0; ht < 2; ++ht)
            #pragma unroll
            for (int e = 0; e < 16; ++e) acc1[ht][e] = 0.f;
        const unsigned short* abp = AbF + (size_t)w*512 + lane*8;
        #pragma unroll
        for (int ks = 0; ks < 14; ++ks) {
            bf16x8 bb = *(const bf16x8*)(abp + (size_t)ks*7*512);
            #pragma unroll
            for (int ht = 0; ht < 2; ++ht) {
                int row = ht*32 + l31;
                int chunk = ks*2 + u;
                bf16x8 a = *(const bf16x8*)(&smem[row*XSW +
                        (((chunk ^ ((row>>1)&31)) & 31)<<3)]);
                acc1[ht] = __builtin_amdgcn_mfma_f32_32x32x16_bf16(a, bb, acc1[ht], 0, 0, 0);
            }
        }
        // z value at reg r: z[h = 32ht + (r&3)+8(r>>2)+4u][node = w*32 + l31]
        // pack pairs (regs 2k, 2k+1) -> bf16 dword; swap halves for z K-frags
        unsigned int Dw[2][8], Xw[2][8];
        #pragma unroll
        for (int ht = 0; ht < 2; ++ht)
            #pragma unroll
            for (int k = 0; k < 8; ++k)
                Dw[ht][k] = cvtpk(acc1[ht][2*k], acc1[ht][2*k+1]);
        #pragma unroll
        for (int ht = 0; ht < 2; ++ht)
            #pragma unroll
            for (int k = 0; k < 8; ++k)
                Xw[ht][k] = (unsigned int)__shfl_xor((int)Dw[ht][k], 32, 64);

        // ---- MFMA2 (SWAPPED): A = gWF (global), B = z-frags (regs) ----
        #pragma unroll
        for (int mt = 0; mt < 2; ++mt)
            #pragma unroll
            for (int e = 0; e < 16; ++e) acc2[mt][e] = 0.f;
        const unsigned short* gp = gWF + lane*8;
        #pragma unroll
        for (int ht = 0; ht < 2; ++ht)
            #pragma unroll
            for (int s = 0; s < 2; ++s) {
                int ksh = ht*2 + s;
                union { unsigned int w4[4]; bf16x8 v; } a2;
                if (s == 0) {
                    a2.w4[0] = u ? Xw[ht][2] : Dw[ht][0];
                    a2.w4[1] = u ? Xw[ht][3] : Dw[ht][1];
                    a2.w4[2] = u ? Dw[ht][2] : Xw[ht][0];
                    a2.w4[3] = u ? Dw[ht][3] : Xw[ht][1];
                } else {
                    a2.w4[0] = u ? Xw[ht][6] : Dw[ht][4];
                    a2.w4[1] = u ? Xw[ht][7] : Dw[ht][5];
                    a2.w4[2] = u ? Dw[ht][6] : Xw[ht][4];
                    a2.w4[3] = u ? Dw[ht][7] : Xw[ht][5];
                }
                #pragma unroll
                for (int mt = 0; mt < 2; ++mt) {
                    bf16x8 bw = *(const bf16x8*)(gp + (size_t)(ksh*2 + mt)*512);
                    acc2[mt] = __builtin_amdgcn_mfma_f32_32x32x16_bf16(bw, a2.v, acc2[mt], 0, 0, 0);
                }
            }

        // ---- residual gather (xT, transposed layout) + gb, then LN stats ----
        // acc2[mt][r] = y[h' = 32mt+(r&3)+8(r>>2)+4u][node nd]
        const f32x4* gb4 = (const f32x4*)(gbF + u*32);
        #pragma unroll
        for (int mt = 0; mt < 2; ++mt)
            #pragma unroll
            for (int rq = 0; rq < 4; ++rq) {
                f32x4 g = gb4[mt*4 + rq];
                #pragma unroll
                for (int j = 0; j < 4; ++j) {
                    int hp = 32*mt + 8*rq + 4*u + j;
                    unsigned short xr = smem[hp*XSW +
                        ((((nd>>3) ^ ((hp>>1)&31)) & 31)<<3) + (nd&7)];
                    acc2[mt][rq*4 + j] += bf2f(xr) + g[j];
                }
            }
        float s1 = 0.f, s2 = 0.f;
        #pragma unroll
        for (int mt = 0; mt < 2; ++mt)
            #pragma unroll
            for (int r = 0; r < 16; ++r) {
                float v = acc2[mt][r];
                s1 += v; s2 += v*v;
            }
        s1 += __shfl_xor(s1, 32, 64);            // combine with partner u-half
        s2 += __shfl_xor(s2, 32, 64);
        mu = s1 * (1.f/64.f);
        float var = s2 * (1.f/64.f) - mu*mu;
        rstd = __builtin_amdgcn_rsqf(var + EPSF);
    }
    __syncthreads();                             // all xT reads complete

    if (w < 7 && nd < NN) {
        // ---- affine + pack 4 consecutive h' -> b64 stores into FSP region ----
        const f32x4* lw4 = (const f32x4*)(lnwF + u*32);
        const f32x4* lb4 = (const f32x4*)(lnbF + u*32);
        #pragma unroll
        for (int mt = 0; mt < 2; ++mt)
            #pragma unroll
            for (int rq = 0; rq < 4; ++rq) {
                f32x4 lw = lw4[mt*4 + rq], lb = lb4[mt*4 + rq];
                float o0 = (acc2[mt][rq*4 + 0] - mu) * rstd * lw[0] + lb[0];
                float o1 = (acc2[mt][rq*4 + 1] - mu) * rstd * lw[1] + lb[1];
                float o2 = (acc2[mt][rq*4 + 2] - mu) * rstd * lw[2] + lb[2];
                float o3 = (acc2[mt][rq*4 + 3] - mu) * rstd * lw[3] + lb[3];
                unsigned int d0 = cvtpk(o0, o1), d1 = cvtpk(o2, o3);
                unsigned long long pk = (unsigned long long)d0 | ((unsigned long long)d1 << 32);
                *(unsigned long long*)(&smem[nd*FSP + 32*mt + 8*rq + 4*u]) = pk;
            }
    }
    __syncthreads();
    // ---- coalesced write-out: full 128 B line per node (b128 chunks) ----
    for (int i = tid; i < NN*8; i += 512) {
        int node = i >> 3, c16 = i & 7;
        uint4 vv = *(const uint4*)(&smem[node*FSP + c16*8]);
        *(uint4*)(xbase + (size_t)node*SH + c16*8) = vv;
    }
}

// ---------------------------------------------------------------------------
// Head futr+bias: out[row,p] = c0[p] + xfut[row,:192] @ C1   (plain writes,
// runs BEFORE k_head_mfma which atomically accumulates the hist GEMM)
// ---------------------------------------------------------------------------
__global__ __launch_bounds__(192) void k_head_futr(const float* __restrict__ xfut,
        const float* __restrict__ C1, const float* __restrict__ c0,
        float* __restrict__ out) {
    __shared__ float C1l[192*PP];   // 36.8 KB
    __shared__ float xfl[4*192];    // 3 KB
    int tid = threadIdx.x;
    int r0 = blockIdx.x * 4;
    for (int i = tid; i < 192*PP; i += 192) C1l[i] = C1[i];
    for (int i = tid; i < 4*192; i += 192) xfl[i] = xfut[(size_t)r0*192 + i];
    __syncthreads();
    int p = tid % PP, rr = tid / PP;
    float acc = c0[p];
    #pragma unroll 8
    for (int j = 0; j < 192; ++j) acc += xfl[rr*192 + j] * C1l[j*PP + p];
    out[(size_t)(r0 + rr)*PP + p] = acc;
}

// ---------------------------------------------------------------------------
// Head hist GEMM (bf16 MFMA): out[row,p] += X[row,:12288] @ hWT^T
// A-op = X rows straight from global; B-op = hWT (L2-hot). Split-K x8.
// ---------------------------------------------------------------------------
#define KSL 1536
__global__ __launch_bounds__(256) void k_head_mfma(const unsigned short* __restrict__ X,
        const unsigned short* __restrict__ hWT, float* __restrict__ out) {
    int tid = threadIdx.x;
    int lane = tid & 63, w = tid >> 6;
    int col = lane & 15, q = lane >> 4;
    int m0 = blockIdx.x*64 + w*16;
    int k0 = blockIdx.y*KSL;
    const unsigned short* xp = X + (size_t)(m0 + col)*SH + k0 + q*8;
    const unsigned short* wp = hWT + (size_t)col*SH + k0 + q*8;
    f32x4 acc[3];
    #pragma unroll
    for (int nt = 0; nt < 3; ++nt) acc[nt] = (f32x4){0.f,0.f,0.f,0.f};
    #pragma unroll 4
    for (int kk = 0; kk < KSL; kk += 32) {
        bf16x8 a = *(const bf16x8*)(xp + kk);
        #pragma unroll
        for (int nt = 0; nt < 3; ++nt) {
            bf16x8 b = *(const bf16x8*)(wp + (size_t)nt*16*SH + kk);
            acc[nt] = __builtin_amdgcn_mfma_f32_16x16x32_bf16(a, b, acc[nt], 0, 0, 0);
        }
    }
    int orow = m0 + q*4;
    #pragma unroll
    for (int nt = 0; nt < 3; ++nt)
        #pragma unroll
        for (int r = 0; r < 4; ++r)
            atomicAdd(&out[(size_t)(orow + r)*PP + nt*16 + col], acc[nt][r]);
}

// ---------------------------------------------------------------------------
extern "C" void kernel_launch(void* const* d_in, const int* in_sizes, int n_in,
                              void* d_out, int out_size, void* d_ws, size_t ws_size,
                              hipStream_t stream) {
    const float* x     = (const float*)d_in[0];
    const float* xfut  = (const float*)d_in[1];
    const float* adj   = (const float*)d_in[2];
    const float* emb   = (const float*)d_in[3];
    const float* alpha = (const float*)d_in[4];
    const float* inw   = (const float*)d_in[5];
    const float* inb   = (const float*)d_in[6];
    const float* pW    = (const float*)d_in[7];
    const float* pb    = (const float*)d_in[8];
    const float* tW    = (const float*)d_in[9];
    const float* tb    = (const float*)d_in[10];
    const float* gW    = (const float*)d_in[11];
    const float* gb    = (const float*)d_in[12];
    const float* lnw   = (const float*)d_in[13];
    const float* lnb   = (const float*)d_in[14];
    const float* fW    = (const float*)d_in[15];
    const float* fb    = (const float*)d_in[16];
    const float* hW    = (const float*)d_in[17];
    const float* hb    = (const float*)d_in[18];
    float* out = (float*)d_out;

    // Workspace layout (~160 MB): bufX 157.3MB + adjacency/weights ~1.6MB
    unsigned short* bufX = (unsigned short*)d_ws;
    float* Amat = (float*)(bufX + XSZ);
    float* Araw = Amat + NN*NN;
    float* dvec = Araw + NN*NN;
    unsigned short* tWb = (unsigned short*)(dvec + NN);
    unsigned short* AbF = tWb + NBLK*SS*SS;
    unsigned short* gWF = AbF + ABFSZ;
    unsigned short* hWT = gWF + NBLK*HH*HH;
    float* C1 = (float*)(hWT + (size_t)PP*SH);
    float* c0 = C1 + 192*PP;
    float* gbF  = c0 + PP;
    float* lnwF = gbF + NBLK*64;
    float* lnbF = lnwF + NBLK*64;

    k_adj_row<<<NN, 64, 0, stream>>>(emb, adj, alpha, Araw, dvec);
    k_adj_scale<<<NN, 256, 0, stream>>>(Araw, dvec, Amat);
    k_prep<<<(NBLK*SS*SS + 255)/256, 256, 0, stream>>>(tW, gW, Amat, gb, lnw, lnb,
                                                       tWb, AbF, gWF, gbF, lnwF, lnbF);
    k_prep2<<<((size_t)PP*SH + 255)/256, 256, 0, stream>>>(hW, fW, fb, hb, hWT, C1, c0);

    // fused stage0 + temporal block 0
    k_stage0_temporal<<<ROWS, 256, 0, stream>>>(x, inw, inb, pW, pb, emb, bufX, tWb, tb);
    k_spatial_fused<<<dim3(SS*BB), 512, 0, stream>>>(bufX, AbF, gWF, gbF, lnwF, lnbF);
    for (int i = 1; i < NBLK; ++i) {
        k_temporal_mfma<<<ROWS, 256, 0, stream>>>(bufX, tWb + (size_t)i*SS*SS, tb + i*SS);
        k_spatial_fused<<<dim3(SS*BB), 512, 0, stream>>>(bufX, AbF, gWF + (size_t)i*HH*HH,
                                                         gbF + i*64, lnwF + i*64, lnbF + i*64);
    }
    k_head_futr<<<ROWS/4, 192, 0, stream>>>(xfut, C1, c0, out);
    k_head_mfma<<<dim3(ROWS/64, 8), 256, 0, stream>>>(bufX, hWT, out);
}